// Round 8
// baseline (58.199 us; speedup 1.0000x reference)
//
#include <hip/hip_runtime.h>
#include <cstddef>
#include <cstdint>

#define BDIM 4
#define HH   64
#define WW   64
#define NG   4
#define GD   64
#define HWSZ 4096
#define NTOT 16384          // BDIM*HWSZ

typedef __attribute__((ext_vector_type(4))) float f32x4;
typedef _Float16 f16x4_t __attribute__((ext_vector_type(4)));
typedef _Float16 f16x8_t __attribute__((ext_vector_type(8)));

// ---------- fused QKV GEMM: no prep, no LDS, no barriers ----------
// D[768 x 16384] = W[768 x 256] * x[256 x 16384], fp16 MFMA, fp32 inputs
// converted to fp16 in registers at load. 128x128 tile per block, 4 waves
// (2m x 2n), 8 K-steps of 32. Blocked fp16 outputs [m/16][n][16].
__global__ __launch_bounds__(256, 2) void qkv_fused_kernel(
    const float* __restrict__ x,
    const float* __restrict__ wq, const float* __restrict__ bq,
    const float* __restrict__ wk, const float* __restrict__ bk,
    const float* __restrict__ wv, const float* __restrict__ bv,
    _Float16* __restrict__ qh, _Float16* __restrict__ kh,
    _Float16* __restrict__ vh)
{
    const int t  = threadIdx.x;
    const int bx = blockIdx.x;
    const int u  = (bx & 7) * 96 + (bx >> 3);   // XCD-chunked (768 = 8*96)
    const int mt = u % 6;                       // consecutive u share nt (x panel)
    const int nt = u / 6;                       // 0..127

    const int l     = t & 63;
    const int wid   = t >> 6;
    const int wm    = wid >> 1, wn = wid & 1;
    const int lrow  = l & 15;
    const int lk8   = (l >> 4) * 8;
    const int lrow4 = (l >> 4) * 4;

    const float* wsel = (mt < 2) ? wq : (mt < 4) ? wk : wv;
    const float* bsel = (mt < 2) ? bq : (mt < 4) ? bk : bv;
    _Float16*    osel = (mt < 2) ? qh : (mt < 4) ? kh : vh;
    const int    mtl  = mt & 1;                 // 0/1 within its 256-row matrix

    // B-side base: n = nt*128 + wn*64 + ni*16 + lrow
    const int n0 = nt * 128 + wn * 64 + lrow;
    const int bi = n0 >> 12;
    const int px = n0 & 4095;
    const float* xb = x + (size_t)bi * 256 * HWSZ + px;

    // acc init with bias
    f32x4 acc[4][4];
    #pragma unroll
    for (int mi = 0; mi < 4; ++mi) {
        const f32x4 bb = *(const f32x4*)&bsel[mtl * 128 + wm * 64 + mi * 16 + lrow4];
        #pragma unroll
        for (int ni = 0; ni < 4; ++ni) acc[mi][ni] = bb;
    }

    for (int kt = 0; kt < 8; ++kt) {
        const int k0 = kt * 32 + lk8;

        // A fragments: W rows are k-contiguous -> 2x f32x4 per frag, cvt in reg
        f16x8_t af[4];
        #pragma unroll
        for (int mi = 0; mi < 4; ++mi) {
            const float* ap = wsel + (size_t)(mtl * 128 + wm * 64 + mi * 16 + lrow) * 256 + k0;
            const float4 a0 = *(const float4*)ap;
            const float4 a1 = *(const float4*)(ap + 4);
            f16x8_t f;
            f[0] = (_Float16)a0.x; f[1] = (_Float16)a0.y;
            f[2] = (_Float16)a0.z; f[3] = (_Float16)a0.w;
            f[4] = (_Float16)a1.x; f[5] = (_Float16)a1.y;
            f[6] = (_Float16)a1.z; f[7] = (_Float16)a1.w;
            af[mi] = f;
        }

        // B fragments: x is [k][n]; per-lane 8 k-strided dwords (lanes cover
        // 16 consecutive pixels -> dense 64B segments per load instruction)
        f16x8_t bf[4];
        #pragma unroll
        for (int ni = 0; ni < 4; ++ni) {
            const float* bp = xb + (size_t)k0 * HWSZ + ni * 16;
            f16x8_t f;
            #pragma unroll
            for (int j = 0; j < 8; ++j) f[j] = (_Float16)bp[(size_t)j * HWSZ];
            bf[ni] = f;
        }

        #pragma unroll
        for (int mi = 0; mi < 4; ++mi)
            #pragma unroll
            for (int ni = 0; ni < 4; ++ni)
                acc[mi][ni] = __builtin_amdgcn_mfma_f32_16x16x32_f16(
                    af[mi], bf[ni], acc[mi][ni], 0, 0, 0);
    }

    // epilogue: D row (m) = (l>>4)*4+reg, col (n) = l&15 — blocked fp16 stores
    #pragma unroll
    for (int ni = 0; ni < 4; ++ni) {
        const size_t ng = (size_t)(nt * 128 + wn * 64 + ni * 16 + lrow);
        #pragma unroll
        for (int mi = 0; mi < 4; ++mi) {
            f16x4_t hv;
            #pragma unroll
            for (int j = 0; j < 4; ++j) hv[j] = (_Float16)acc[mi][ni][j];
            const int chunk = mtl * 8 + wm * 4 + mi;     // 0..15
            *(f16x4_t*)&osel[((size_t)chunk * NTOT + ng) * 16 + lrow4] = hv;
        }
    }
}

// ---------- local grouped attention: q,k,v fp16 blocked; fp32 math ----------
__global__ __launch_bounds__(256) void loc_attn_kernel(
    const _Float16* __restrict__ qh, const _Float16* __restrict__ kh,
    const _Float16* __restrict__ vh, float* __restrict__ out)
{
    const int t   = threadIdx.x;
    const int bx0 = blockIdx.x;
    const int bx  = (bx0 & 7) * 128 + (bx0 >> 3);
    const int h = bx & 63;
    const int g = (bx >> 6) & 3;
    const int b = bx >> 8;

    const int wl  = t & 15;
    const int c   = (t >> 4) & 3;
    const int wid = t >> 6;
    const int w   = wid * 16 + wl;

    const int ck = g * 4 + c;                    // chunk index 0..15
    const size_t n = (size_t)b * HWSZ + h * 64 + w;

    float qf[16];
    {
        const _Float16* qp = &qh[((size_t)ck * NTOT + n) * 16];
        const f16x8_t q0 = *(const f16x8_t*)qp;
        const f16x8_t q1 = *(const f16x8_t*)(qp + 8);
        #pragma unroll
        for (int j = 0; j < 8; ++j) { qf[j] = (float)q0[j]; qf[8 + j] = (float)q1[j]; }
    }

    float logit[9];
    #pragma unroll
    for (int p = 0; p < 9; ++p) {
        const int dh = p / 3 - 1, dw = p % 3 - 1;
        const int hh = h + dh, ww2 = w + dw;
        float part = 0.f;
        if (hh >= 0 && hh < HH && ww2 >= 0 && ww2 < WW) {
            const size_t nn = (size_t)b * HWSZ + hh * 64 + ww2;
            const _Float16* kp = &kh[((size_t)ck * NTOT + nn) * 16];
            const f16x8_t k0 = *(const f16x8_t*)kp;
            const f16x8_t k1 = *(const f16x8_t*)(kp + 8);
            #pragma unroll
            for (int j = 0; j < 8; ++j)
                part += qf[j] * (float)k0[j] + qf[8 + j] * (float)k1[j];
        }
        part += __shfl_xor(part, 16, 64);
        part += __shfl_xor(part, 32, 64);
        logit[p] = part;
    }

    float mx = logit[0];
    #pragma unroll
    for (int p = 1; p < 9; ++p) mx = fmaxf(mx, logit[p]);
    float a[9];
    float s = 0.f;
    #pragma unroll
    for (int p = 0; p < 9; ++p) { a[p] = __expf(logit[p] - mx); s += a[p]; }
    const float inv = 1.f / s;
    #pragma unroll
    for (int p = 0; p < 9; ++p) a[p] *= inv;

    float acc[16];
    #pragma unroll
    for (int dd = 0; dd < 16; ++dd) acc[dd] = 0.f;
    #pragma unroll
    for (int p = 0; p < 9; ++p) {
        const int dh = p / 3 - 1, dw = p % 3 - 1;
        const int hh = h + dh, ww2 = w + dw;
        if (hh < 0 || hh >= HH || ww2 < 0 || ww2 >= WW) continue;
        const size_t nn = (size_t)b * HWSZ + hh * 64 + ww2;
        const _Float16* vp = &vh[((size_t)ck * NTOT + nn) * 16];
        const f16x8_t v0 = *(const f16x8_t*)vp;
        const f16x8_t v1 = *(const f16x8_t*)(vp + 8);
        const float ap = a[p];
        #pragma unroll
        for (int j = 0; j < 8; ++j) {
            acc[j]     += ap * (float)v0[j];
            acc[8 + j] += ap * (float)v1[j];
        }
    }

    const int obase = b * 256 + g * 64 + c * 16;
    const int off = h * 64 + w;
    #pragma unroll
    for (int dd = 0; dd < 16; ++dd)
        out[(size_t)(obase + dd) * HWSZ + off] = acc[dd];
}

extern "C" void kernel_launch(void* const* d_in, const int* in_sizes, int n_in,
                              void* d_out, int out_size, void* d_ws, size_t ws_size,
                              hipStream_t stream) {
    const float* x  = (const float*)d_in[0];
    const float* wq = (const float*)d_in[1];
    const float* bq = (const float*)d_in[2];
    const float* wk = (const float*)d_in[3];
    const float* bk = (const float*)d_in[4];
    const float* wv = (const float*)d_in[5];
    const float* bv = (const float*)d_in[6];
    float* out = (float*)d_out;

    char* ws = (char*)d_ws;
    _Float16* qh = (_Float16*)ws;                      //  8.39 MB
    _Float16* kh = (_Float16*)(ws + 8388608);          //  8.39 MB
    _Float16* vh = (_Float16*)(ws + 16777216);         //  8.39 MB

    qkv_fused_kernel<<<dim3(768), 256, 0, stream>>>(x, wq, bq, wk, bk, wv, bv,
                                                    qh, kh, vh);
    loc_attn_kernel<<<dim3(1024), 256, 0, stream>>>(qh, kh, vh, out);
}

// Round 9
// 34.066 us; speedup vs baseline: 1.7084x; 1.7084x over previous
//
#include <hip/hip_runtime.h>
#include <cstddef>
#include <cstdint>

#define BDIM 4
#define HH   64
#define WW   64
#define NG   4
#define GD   64
#define HWSZ 4096
#define NTOT 16384          // BDIM*HWSZ
#define CIN  256

typedef __attribute__((ext_vector_type(4))) float f32x4;
typedef _Float16 f16x4_t __attribute__((ext_vector_type(4)));
typedef _Float16 f16x8_t __attribute__((ext_vector_type(8)));

__device__ __forceinline__ void lds_load16(const void* g, void* l) {
    __builtin_amdgcn_global_load_lds(
        (const __attribute__((address_space(1))) unsigned int*)g,
        (__attribute__((address_space(3))) unsigned int*)l, 16, 0, 0);
}

// ---------- fused QKV GEMM: fp32 inputs staged to LDS, fp16 MFMA ----------
// D[768 x 16384] = W[768 x 256] * x[256 x 16384]. 128x128 tile, 4 waves,
// BK=32, 8 K-steps. Staging via global_load_lds w16 with source-preswizzle:
//   A (W): 16B k-block kb ^= (m&7)      -> b128 frag reads 2-way (free)
//   B (x): 16B px-block pxb ^= (k>>3)<<2 -> b32 k-gather reads 2-way
// fp32->fp16 conversion happens in registers at fragment build.
// Blocked fp16 outputs qh/kh/vh [m/16][n][16].
__global__ __launch_bounds__(256) void qkv_gemm_kernel(
    const float* __restrict__ x,
    const float* __restrict__ wq, const float* __restrict__ bq,
    const float* __restrict__ wk, const float* __restrict__ bk,
    const float* __restrict__ wv, const float* __restrict__ bv,
    _Float16* __restrict__ qh, _Float16* __restrict__ kh,
    _Float16* __restrict__ vh)
{
    __shared__ float As[128 * 32];   // [m][kb^(m&7) blocks] 16 KB
    __shared__ float Bs[32 * 128];   // [k][pxb^((k>>3)<<2) blocks] 16 KB

    const int t  = threadIdx.x;
    const int bx = blockIdx.x;
    const int u  = (bx & 7) * 96 + (bx >> 3);   // XCD-chunked (768 = 8*96)
    const int mt = u % 6;                       // consecutive u share nt (x panel)
    const int nt = u / 6;                       // 0..127

    const int l     = t & 63;
    const int wid   = t >> 6;
    const int wm    = wid >> 1, wn = wid & 1;
    const int lrow  = l & 15;
    const int grp   = l >> 4;                   // 0..3
    const int lk8   = grp * 8;
    const int lrow4 = grp * 4;

    const float* wsel = (mt < 2) ? wq : (mt < 4) ? wk : wv;
    const float* bsel = (mt < 2) ? bq : (mt < 4) ? bk : bv;
    _Float16*    osel = (mt < 2) ? qh : (mt < 4) ? kh : vh;
    const int    mtl  = mt & 1;

    const int bi  = nt >> 5;
    const int px0 = (nt & 31) * 128;
    const float* xb = x + (size_t)bi * CIN * HWSZ + px0;

    // acc init with bias (fp32 from global; small, L2-hot)
    f32x4 acc[4][4];
    #pragma unroll
    for (int mi = 0; mi < 4; ++mi) {
        const f32x4 bb = *(const f32x4*)&bsel[mtl * 128 + wm * 64 + mi * 16 + lrow4];
        #pragma unroll
        for (int ni = 0; ni < 4; ++ni) acc[mi][ni] = bb;
    }

    // staging source pointers (4 issues x 16B per operand per K-step)
    const float* asrc[4];
    const float* bsrc[4];
    #pragma unroll
    for (int i = 0; i < 4; ++i) {
        const int w16 = i * 256 + t;
        {   // A: dest (m = w16>>3, kb = w16&7); source k-block kb ^ (m&7)
            const int m  = w16 >> 3;
            const int kb = w16 & 7;
            asrc[i] = wsel + (size_t)(mtl * 128 + m) * CIN + ((kb ^ (m & 7)) * 4);
        }
        {   // B: dest (k = w16>>5, pxb = w16&31); source px-block pxb ^ ((k>>3)<<2)
            const int k   = w16 >> 5;
            const int pxb = w16 & 31;
            bsrc[i] = xb + (size_t)k * HWSZ + ((pxb ^ ((k >> 3) << 2)) * 4);
        }
    }

    for (int kt = 0; kt < 8; ++kt) {
        #pragma unroll
        for (int i = 0; i < 4; ++i) {
            lds_load16(asrc[i] + kt * 32, As + (i * 256 + t) * 4);
            lds_load16(bsrc[i] + (size_t)kt * 32 * HWSZ, Bs + (i * 256 + t) * 4);
        }
        __syncthreads();

        // A fragments: two swizzled b128 fp32 reads + cvt
        f16x8_t af[4];
        #pragma unroll
        for (int mi = 0; mi < 4; ++mi) {
            const int m  = wm * 64 + mi * 16 + lrow;
            const int s  = m & 7;
            const f32x4 a0 = *(const f32x4*)&As[m * 32 + ((grp * 2) ^ s) * 4];
            const f32x4 a1 = *(const f32x4*)&As[m * 32 + ((grp * 2 + 1) ^ s) * 4];
            f16x8_t f;
            #pragma unroll
            for (int j = 0; j < 4; ++j) { f[j] = (_Float16)a0[j]; f[4 + j] = (_Float16)a1[j]; }
            af[mi] = f;
        }

        // B fragments: 8x swizzled b32 k-gather + cvt
        f16x8_t bf[4];
        #pragma unroll
        for (int ni = 0; ni < 4; ++ni) {
            const int px   = wn * 64 + ni * 16 + lrow;
            const int base = ((px >> 2) ^ (grp << 2)) * 4 + (px & 3);
            f16x8_t f;
            #pragma unroll
            for (int j = 0; j < 8; ++j) f[j] = (_Float16)Bs[(lk8 + j) * 128 + base];
            bf[ni] = f;
        }

        #pragma unroll
        for (int mi = 0; mi < 4; ++mi)
            #pragma unroll
            for (int ni = 0; ni < 4; ++ni)
                acc[mi][ni] = __builtin_amdgcn_mfma_f32_16x16x32_f16(
                    af[mi], bf[ni], acc[mi][ni], 0, 0, 0);
        __syncthreads();
    }

    // epilogue: D row (m) = grp*4+reg, col (n) = l&15 — blocked fp16 stores
    #pragma unroll
    for (int ni = 0; ni < 4; ++ni) {
        const size_t ng = (size_t)(nt * 128 + wn * 64 + ni * 16 + lrow);
        #pragma unroll
        for (int mi = 0; mi < 4; ++mi) {
            f16x4_t hv;
            #pragma unroll
            for (int j = 0; j < 4; ++j) hv[j] = (_Float16)acc[mi][ni][j];
            const int chunk = mtl * 8 + wm * 4 + mi;     // 0..15
            *(f16x4_t*)&osel[((size_t)chunk * NTOT + ng) * 16 + lrow4] = hv;
        }
    }
}

// ---------- local grouped attention: q,k,v fp16 blocked; fp32 math ----------
__global__ __launch_bounds__(256) void loc_attn_kernel(
    const _Float16* __restrict__ qh, const _Float16* __restrict__ kh,
    const _Float16* __restrict__ vh, float* __restrict__ out)
{
    const int t   = threadIdx.x;
    const int bx0 = blockIdx.x;
    const int bx  = (bx0 & 7) * 128 + (bx0 >> 3);
    const int h = bx & 63;
    const int g = (bx >> 6) & 3;
    const int b = bx >> 8;

    const int wl  = t & 15;
    const int c   = (t >> 4) & 3;
    const int wid = t >> 6;
    const int w   = wid * 16 + wl;

    const int ck = g * 4 + c;                    // chunk index 0..15
    const size_t n = (size_t)b * HWSZ + h * 64 + w;

    float qf[16];
    {
        const _Float16* qp = &qh[((size_t)ck * NTOT + n) * 16];
        const f16x8_t q0 = *(const f16x8_t*)qp;
        const f16x8_t q1 = *(const f16x8_t*)(qp + 8);
        #pragma unroll
        for (int j = 0; j < 8; ++j) { qf[j] = (float)q0[j]; qf[8 + j] = (float)q1[j]; }
    }

    float logit[9];
    #pragma unroll
    for (int p = 0; p < 9; ++p) {
        const int dh = p / 3 - 1, dw = p % 3 - 1;
        const int hh = h + dh, ww2 = w + dw;
        float part = 0.f;
        if (hh >= 0 && hh < HH && ww2 >= 0 && ww2 < WW) {
            const size_t nn = (size_t)b * HWSZ + hh * 64 + ww2;
            const _Float16* kp = &kh[((size_t)ck * NTOT + nn) * 16];
            const f16x8_t k0 = *(const f16x8_t*)kp;
            const f16x8_t k1 = *(const f16x8_t*)(kp + 8);
            #pragma unroll
            for (int j = 0; j < 8; ++j)
                part += qf[j] * (float)k0[j] + qf[8 + j] * (float)k1[j];
        }
        part += __shfl_xor(part, 16, 64);
        part += __shfl_xor(part, 32, 64);
        logit[p] = part;
    }

    float mx = logit[0];
    #pragma unroll
    for (int p = 1; p < 9; ++p) mx = fmaxf(mx, logit[p]);
    float a[9];
    float s = 0.f;
    #pragma unroll
    for (int p = 0; p < 9; ++p) { a[p] = __expf(logit[p] - mx); s += a[p]; }
    const float inv = 1.f / s;
    #pragma unroll
    for (int p = 0; p < 9; ++p) a[p] *= inv;

    float acc[16];
    #pragma unroll
    for (int dd = 0; dd < 16; ++dd) acc[dd] = 0.f;
    #pragma unroll
    for (int p = 0; p < 9; ++p) {
        const int dh = p / 3 - 1, dw = p % 3 - 1;
        const int hh = h + dh, ww2 = w + dw;
        if (hh < 0 || hh >= HH || ww2 < 0 || ww2 >= WW) continue;
        const size_t nn = (size_t)b * HWSZ + hh * 64 + ww2;
        const _Float16* vp = &vh[((size_t)ck * NTOT + nn) * 16];
        const f16x8_t v0 = *(const f16x8_t*)vp;
        const f16x8_t v1 = *(const f16x8_t*)(vp + 8);
        const float ap = a[p];
        #pragma unroll
        for (int j = 0; j < 8; ++j) {
            acc[j]     += ap * (float)v0[j];
            acc[8 + j] += ap * (float)v1[j];
        }
    }

    const int obase = b * 256 + g * 64 + c * 16;
    const int off = h * 64 + w;
    #pragma unroll
    for (int dd = 0; dd < 16; ++dd)
        out[(size_t)(obase + dd) * HWSZ + off] = acc[dd];
}

extern "C" void kernel_launch(void* const* d_in, const int* in_sizes, int n_in,
                              void* d_out, int out_size, void* d_ws, size_t ws_size,
                              hipStream_t stream) {
    const float* x  = (const float*)d_in[0];
    const float* wq = (const float*)d_in[1];
    const float* bq = (const float*)d_in[2];
    const float* wk = (const float*)d_in[3];
    const float* bk = (const float*)d_in[4];
    const float* wv = (const float*)d_in[5];
    const float* bv = (const float*)d_in[6];
    float* out = (float*)d_out;

    char* ws = (char*)d_ws;
    _Float16* qh = (_Float16*)ws;                      //  8.39 MB
    _Float16* kh = (_Float16*)(ws + 8388608);          //  8.39 MB
    _Float16* vh = (_Float16*)(ws + 16777216);         //  8.39 MB

    qkv_gemm_kernel<<<dim3(768), 256, 0, stream>>>(x, wq, bq, wk, bk, wv, bv,
                                                   qh, kh, vh);
    loc_attn_kernel<<<dim3(1024), 256, 0, stream>>>(qh, kh, vh, out);
}